// Round 1
// baseline (627.199 us; speedup 1.0000x reference)
//
#include <hip/hip_runtime.h>

// Attention with policy-softmax, MI355X (gfx950).
// Shapes: B=16, N=1024, C=768, H=12, hd=64.
// R7: attn latency pipeline — c-loop split into 16 half-steps (64 keys).
//   K double-buffered in registers (prefetch issued right after current
//   S-MFMAs), VT loads hoisted to half-step top (covered by S-MFMA+softmax),
//   sP shrunk to per-half [4][2][16][72] (LDS 38.9->22.5KB), chunk-start
//   stagger by head group to de-correlate same-XCD streams, exp2 via
//   __builtin_amdgcn_exp2f. GEMMs unchanged (128x128, global_load_lds w=16).

#define NB 16
#define NN 1024
#define NC 768
#define NH 12
#define HD 64
#define NM (NB*NN)      // 16384
#define QKVC (3*NC)     // 2304
#define QSCALE 0.18033688011112042f   // 0.125 * log2(e)

typedef _Float16 f16;
typedef _Float16 f16x8 __attribute__((ext_vector_type(8)));
typedef _Float16 f16x4 __attribute__((ext_vector_type(4)));
typedef __fp16 fp16x2 __attribute__((ext_vector_type(2)));   // cvt_pkrtz native type
typedef float f32x4 __attribute__((ext_vector_type(4)));

#if __has_builtin(__builtin_amdgcn_exp2f)
#define EXP2(x) __builtin_amdgcn_exp2f(x)
#else
#define EXP2(x) exp2f(x)
#endif

__device__ inline f16x8 as_f16x8(uint4 u){
  union { uint4 u; f16x8 h; } v; v.u = u; return v.h;
}

// async global->LDS, 16B per lane; lds ptr must be wave-uniform (lane l lands at +l*16B)
__device__ inline void gl_lds16(const f16* g, f16* l){
  __builtin_amdgcn_global_load_lds(
      (const __attribute__((address_space(1))) void*)g,
      (__attribute__((address_space(3))) void*)l, 16, 0, 0);
}

// ---------------- fp32 -> f16 convert ----------------
__global__ void cvt_f32_f16(const float* __restrict__ in, f16* __restrict__ out, int n4){
  int i = blockIdx.x*blockDim.x + threadIdx.x;
  if (i < n4){
    float4 v = ((const float4*)in)[i];
    f16x4 h; h[0]=(f16)v.x; h[1]=(f16)v.y; h[2]=(f16)v.z; h[3]=(f16)v.w;
    ((f16x4*)out)[i] = h;
  }
}

// ---------------- QKV GEMM: [16384,768] x [2304,768]^T, 128x128 tile ----------------
__launch_bounds__(256)
__global__ void gemm_qkv(const f16* __restrict__ X, const f16* __restrict__ W,
                         f16* __restrict__ Q, f16* __restrict__ K, f16* __restrict__ VT){
  __shared__ f16 sA[128*32];   // 8 KB, row-major [row][k], stride 32
  __shared__ f16 sB[128*32];
  const int R0 = blockIdx.y*128, C0 = blockIdx.x*128;
  const int t = threadIdx.x;
  const int w = t >> 6, l = t & 63, quad = l >> 4, lr = l & 15;
  const int wr = w >> 1, wc = w & 1;
  const int row0 = t >> 2, kc0 = (t & 3)*8;
  f32x4 acc[4][4] = {};
  for (int bk = 0; bk < NC; bk += 32){
#pragma unroll
    for (int r = 0; r < 2; r++){
      int row = r*64 + row0;
      gl_lds16(X + (size_t)(R0 + row)*NC + bk + kc0, sA + r*2048 + w*512);
      gl_lds16(W + (size_t)(C0 + row)*NC + bk + kc0, sB + r*2048 + w*512);
    }
    __syncthreads();
    f16x8 af[4], bf[4];
#pragma unroll
    for (int mt = 0; mt < 4; mt++)
      af[mt] = as_f16x8(*(const uint4*)(sA + (wr*64 + mt*16 + lr)*32 + quad*8));
#pragma unroll
    for (int nt = 0; nt < 4; nt++)
      bf[nt] = as_f16x8(*(const uint4*)(sB + (wc*64 + nt*16 + lr)*32 + quad*8));
#pragma unroll
    for (int mt = 0; mt < 4; mt++)
#pragma unroll
      for (int nt = 0; nt < 4; nt++)
        acc[mt][nt] = __builtin_amdgcn_mfma_f32_16x16x32_f16(af[mt], bf[nt], acc[mt][nt], 0, 0, 0);
    __syncthreads();
  }
  // scatter into Q / K / V^T. type uniform per block (128 | 768).
  const int type = C0 / NC;
#pragma unroll
  for (int nt = 0; nt < 4; nt++){
    int colg = C0 + wc*64 + nt*16 + lr;
    int rem  = colg - type*NC;
    int hh = rem >> 6, d = rem & 63;
#pragma unroll
    for (int mt = 0; mt < 4; mt++)
#pragma unroll
      for (int i = 0; i < 4; i++){
        int row = R0 + wr*64 + mt*16 + quad*4 + i;
        int bb = row >> 10, np = row & 1023;
        int bh = bb*NH + hh;
        float a = acc[mt][nt][i];
        if (type == 0)      Q[(bh << 16) + (np << 6) + d] = (f16)(a * QSCALE);
        else if (type == 1) K[(bh << 16) + (np << 6) + d] = (f16)a;
        else                VT[(bh << 16) + (d << 10) + np] = (f16)a;
      }
  }
}

// ---------------- Vsum: column sums of V per (b,h) ----------------
__global__ void vsum_kernel(const f16* __restrict__ VT, float* __restrict__ vsum){
  int bh = blockIdx.x;
  int t = threadIdx.x;
  int row = t >> 2, part = t & 3;
  const uint4* p = (const uint4*)(VT + ((size_t)bh << 16) + row*NN + part*256);
  float s = 0.f;
#pragma unroll
  for (int i = 0; i < 32; i++){
    f16x8 v = as_f16x8(p[i]);
#pragma unroll
    for (int j = 0; j < 8; j++) s += (float)v[j];
  }
  __shared__ float sR[64][4];
  sR[row][part] = s;
  __syncthreads();
  if (t < 64) vsum[bh*64 + t] = sR[t][0] + sR[t][1] + sR[t][2] + sR[t][3];
}

// ---------------- fused policy-softmax attention (no-max-subtract) ----------------
// Grid: 1536 blocks; decode bh = blk % 192 (XCD swizzle: same-bh q-blocks land on
// one XCD), qt = blk / 192. 256 thr = 4 independent waves (32 queries each).
// Q pre-scaled by 0.125*log2e -> e = exp2(acc). Pipeline: 16 half-steps of 64
// keys; K double-buffered in regs (prefetch after S-MFMAs), VT loads issued at
// half-step top. l via ones-MFMA. Epilogue restores exact reference eps
// semantics: out = (O + eps/N*E*Vsum)/(l + eps*E), E = exp2(rowmax).

// --- per-half-step building blocks (expand in attn_kernel scope) ---
#define KLOAD(BUF, CC, HH)                                                    \
  {                                                                           \
    const f16* kp_ = Kln + (size_t)(((CC)*128 + (HH)*64)*HD);                 \
    _Pragma("unroll")                                                         \
    for (int ct = 0; ct < 4; ct++){                                           \
      BUF[2*ct]   = *(const uint4*)(kp_ + ct*16*HD);                          \
      BUF[2*ct+1] = *(const uint4*)(kp_ + ct*16*HD + 32);                     \
    }                                                                         \
  }

#define VTLOAD(CC, HH)                                                        \
  {                                                                           \
    const int off_ = (CC)*128 + (HH)*64;                                      \
    _Pragma("unroll")                                                         \
    for (int nt = 0; nt < 4; nt++){                                           \
      vt[2*nt]   = *(const uint4*)(VTn[nt] + off_);                           \
      vt[2*nt+1] = *(const uint4*)(VTn[nt] + off_ + 32);                      \
    }                                                                         \
  }

#define SQK(KBUF)                                                             \
  _Pragma("unroll")                                                           \
  for (int ct = 0; ct < 4; ct++){                                             \
    f16x8 k0_ = as_f16x8(KBUF[2*ct]);                                         \
    f16x8 k1_ = as_f16x8(KBUF[2*ct+1]);                                       \
    accA[ct] = __builtin_amdgcn_mfma_f32_16x16x32_f16(k0_, qf[0][0], accA[ct], 0, 0, 0); \
    accA[ct] = __builtin_amdgcn_mfma_f32_16x16x32_f16(k1_, qf[0][1], accA[ct], 0, 0, 0); \
    accB[ct] = __builtin_amdgcn_mfma_f32_16x16x32_f16(k0_, qf[1][0], accB[ct], 0, 0, 0); \
    accB[ct] = __builtin_amdgcn_mfma_f32_16x16x32_f16(k1_, qf[1][1], accB[ct], 0, 0, 0); \
  }

#define SMAX(CC, HH)                                                          \
  {                                                                           \
    const int key0h = (CC)*128 + (HH)*64;                                     \
    float mA = m_run[0], mB = m_run[1];                                       \
    if ((CC) != qt || (HH) != (w >> 1)){                                      \
      _Pragma("unroll")                                                       \
      for (int ct = 0; ct < 4; ct++){                                         \
        const int kb = ct*16 + quad*4;                                        \
        float4 pol4 = *(const float4*)&sPol[key0h + kb];                      \
        const float* p4 = (const float*)&pol4;                                \
        mA = fmaxf(mA, fmaxf(fmaxf(accA[ct][0], accA[ct][1]), fmaxf(accA[ct][2], accA[ct][3]))); \
        mB = fmaxf(mB, fmaxf(fmaxf(accB[ct][0], accB[ct][1]), fmaxf(accB[ct][2], accB[ct][3]))); \
        union { f16x4 v; fp16x2 h[2]; } uA, uB;                               \
        uA.h[0] = __builtin_amdgcn_cvt_pkrtz(EXP2(accA[ct][0])*p4[0], EXP2(accA[ct][1])*p4[1]); \
        uA.h[1] = __builtin_amdgcn_cvt_pkrtz(EXP2(accA[ct][2])*p4[2], EXP2(accA[ct][3])*p4[3]); \
        uB.h[0] = __builtin_amdgcn_cvt_pkrtz(EXP2(accB[ct][0])*p4[0], EXP2(accB[ct][1])*p4[1]); \
        uB.h[1] = __builtin_amdgcn_cvt_pkrtz(EXP2(accB[ct][2])*p4[2], EXP2(accB[ct][3])*p4[3]); \
        *(f16x4*)&sP[w][0][lr][kb] = uA.v;                                    \
        *(f16x4*)&sP[w][1][lr][kb] = uB.v;                                    \
      }                                                                       \
    } else {                                                                  \
      _Pragma("unroll")                                                       \
      for (int ct = 0; ct < 4; ct++){                                         \
        const int kb = ct*16 + quad*4;                                        \
        float4 pol4 = *(const float4*)&sPol[key0h + kb];                      \
        const float* p4 = (const float*)&pol4;                                \
        float eA[4], eB[4];                                                   \
        _Pragma("unroll")                                                     \
        for (int i2 = 0; i2 < 4; i2++){                                       \
          int kg = key0h + kb + i2;                                           \
          float polA = (kg == qrow)      ? 1.0f : p4[i2];                     \
          float polB = (kg == qrow + 16) ? 1.0f : p4[i2];                     \
          mA = fmaxf(mA, accA[ct][i2]); mB = fmaxf(mB, accB[ct][i2]);         \
          eA[i2] = EXP2(accA[ct][i2]) * polA;                                 \
          eB[i2] = EXP2(accB[ct][i2]) * polB;                                 \
        }                                                                     \
        union { f16x4 v; fp16x2 h[2]; } uA, uB;                               \
        uA.h[0] = __builtin_amdgcn_cvt_pkrtz(eA[0], eA[1]);                   \
        uA.h[1] = __builtin_amdgcn_cvt_pkrtz(eA[2], eA[3]);                   \
        uB.h[0] = __builtin_amdgcn_cvt_pkrtz(eB[0], eB[1]);                   \
        uB.h[1] = __builtin_amdgcn_cvt_pkrtz(eB[2], eB[3]);                   \
        *(f16x4*)&sP[w][0][lr][kb] = uA.v;                                    \
        *(f16x4*)&sP[w][1][lr][kb] = uB.v;                                    \
      }                                                                       \
    }                                                                         \
    m_run[0] = mA; m_run[1] = mB;                                             \
  }

#define PVACC                                                                 \
  _Pragma("unroll")                                                           \
  for (int s8g = 0; s8g < 2; s8g++){                                          \
    f16x8 pfA = as_f16x8(*(const uint4*)&sP[w][0][lr][s8g*32 + quad*8]);      \
    f16x8 pfB = as_f16x8(*(const uint4*)&sP[w][1][lr][s8g*32 + quad*8]);      \
    acc_l[0] = __builtin_amdgcn_mfma_f32_16x16x32_f16(pfA, ones, acc_l[0], 0, 0, 0); \
    acc_l[1] = __builtin_amdgcn_mfma_f32_16x16x32_f16(pfB, ones, acc_l[1], 0, 0, 0); \
    _Pragma("unroll")                                                         \
    for (int nt = 0; nt < 4; nt++){                                           \
      f16x8 vf = as_f16x8(vt[2*nt + s8g]);                                    \
      o[0][nt] = __builtin_amdgcn_mfma_f32_16x16x32_f16(pfA, vf, o[0][nt], 0, 0, 0); \
      o[1][nt] = __builtin_amdgcn_mfma_f32_16x16x32_f16(pfB, vf, o[1][nt], 0, 0, 0); \
    }                                                                         \
  }

__launch_bounds__(256, 3)
__global__ void attn_kernel(const f16* __restrict__ Q, const f16* __restrict__ K,
                            const f16* __restrict__ VT, const float* __restrict__ policy,
                            const float* __restrict__ vsum, f16* __restrict__ O){
  __shared__ f16 sP[4][2][16][72];     // 18432 B (per-half P tile; 72 = 64 + 8 pad, 144B rows)
  __shared__ float sPol[1024];         // 4096 B

  const int blk = blockIdx.x;
  const int bh = blk % (NB*NH);        // stride-192 => same XCD for all qt of a bh
  const int qt = blk / (NB*NH);
  const int b = bh / NH;
  const size_t base = (size_t)bh << 16;

  const int t = threadIdx.x;
  const int w = t >> 6, l = t & 63, quad = l >> 4, lr = l & 15;
  const int q0 = qt*128 + w*32;
  const int qrow = q0 + lr;
  const int h = bh - b*NH;

  *(float4*)&sPol[t*4] = *(const float4*)(policy + b*NN + t*4);

  // Q fragments (pre-scaled), contiguous 16B global reads
  f16x8 qf[2][2];
#pragma unroll
  for (int tq = 0; tq < 2; tq++)
#pragma unroll
    for (int hf = 0; hf < 2; hf++)
      qf[tq][hf] = as_f16x8(*(const uint4*)(Q + base + (size_t)(q0 + tq*16 + lr)*HD + hf*32 + quad*8));

  float vs[4];
#pragma unroll
  for (int nt = 0; nt < 4; nt++) vs[nt] = vsum[bh*64 + nt*16 + lr];

  f16x8 ones;
#pragma unroll
  for (int j = 0; j < 8; j++) ones[j] = (f16)1.0f;

  float m_run[2] = {-INFINITY, -INFINITY};
  f32x4 acc_l[2] = {};
  f32x4 o[2][4] = {};

  // per-lane base pointers (loop bodies use uniform offsets on top of these)
  const f16* Kln = K + base + (size_t)lr*HD + quad*8;
  const f16* VTn[4];
#pragma unroll
  for (int nt = 0; nt < 4; nt++) VTn[nt] = VT + base + (size_t)(nt*16 + lr)*NN + quad*8;

  // stagger chunk start per head-group: same-bh blocks (same XCD) stay in
  // phase for L2 reuse; different bh on an XCD de-correlate.
  const int c0 = (bh >> 3) & 7;
  int c = c0;

  uint4 kA[8], kB[8], vt[8];
  KLOAD(kA, c0, 0);                    // prologue K prefetch (half-step 0)

  __syncthreads();   // sPol ready (also drains prologue loads — once, harmless)

#pragma unroll 1
  for (int i = 0; i < 8; i++){
    const int cn = (c + 1) & 7;
    // ---- half-step 0: consume kA, prefetch kB (this chunk, half 1)
    VTLOAD(c, 0);
    {
      f32x4 accA[4] = {}, accB[4] = {};
      SQK(kA);
      KLOAD(kB, c, 1);
      SMAX(c, 0);
    }
    PVACC;
    // ---- half-step 1: consume kB, prefetch kA (next chunk, half 0)
    VTLOAD(c, 1);
    {
      f32x4 accA[4] = {}, accB[4] = {};
      SQK(kB);
      KLOAD(kA, cn, 0);
      SMAX(c, 1);
    }
    PVACC;
    c = cn;
  }

  // ---- epilogue: out = (O + eps/N * E * Vsum) / (l + eps * E)
#pragma unroll
  for (int tq = 0; tq < 2; tq++){
    float mq = m_run[tq];
    mq = fmaxf(mq, __shfl_xor(mq, 16));
    mq = fmaxf(mq, __shfl_xor(mq, 32));   // per-query (lr) global max, all lanes
#pragma unroll
    for (int i = 0; i < 4; i++){
      float mi = __shfl(mq, quad*4 + i);  // max for query row quad*4+i
      float E  = EXP2(mi);
      float li = acc_l[tq][i];            // row-sum for this query
      float inv = 1.0f / (li + 1e-6f*E);
      float ec  = (1e-6f/1024.0f)*E;
      int row = q0 + tq*16 + quad*4 + i;
      f16* op = O + (size_t)(b*NN + row)*NC + h*HD;
#pragma unroll
      for (int nt = 0; nt < 4; nt++)
        op[nt*16 + lr] = (f16)((o[tq][nt][i] + ec*vs[nt]) * inv);
    }
  }
}

// ---------------- proj GEMM: [16384,768] x [768,768]^T + bias -> fp32, 128x128 ----------------
__launch_bounds__(256)
__global__ void gemm_proj(const f16* __restrict__ A, const f16* __restrict__ W,
                          const float* __restrict__ bias, float* __restrict__ out){
  __shared__ f16 sA[128*32];
  __shared__ f16 sB[128*32];
  const int R0 = blockIdx.y*128, C0 = blockIdx.x*128;
  const int t = threadIdx.x;
  const int w = t >> 6, l = t & 63, quad = l >> 4, lr = l & 15;
  const int wr = w >> 1, wc = w & 1;
  const int row0 = t >> 2, kc0 = (t & 3)*8;
  f32x4 acc[4][4] = {};
  for (int bk = 0; bk < NC; bk += 32){
#pragma unroll
    for (int r = 0; r < 2; r++){
      int row = r*64 + row0;
      gl_lds16(A + (size_t)(R0 + row)*NC + bk + kc0, sA + r*2048 + w*512);
      gl_lds16(W + (size_t)(C0 + row)*NC + bk + kc0, sB + r*2048 + w*512);
    }
    __syncthreads();
    f16x8 af[4], bf[4];
#pragma unroll
    for (int mt = 0; mt < 4; mt++)
      af[mt] = as_f16x8(*(const uint4*)(sA + (wr*64 + mt*16 + lr)*32 + quad*8));
#pragma unroll
    for (int nt = 0; nt < 4; nt++)
      bf[nt] = as_f16x8(*(const uint4*)(sB + (wc*64 + nt*16 + lr)*32 + quad*8));
#pragma unroll
    for (int mt = 0; mt < 4; mt++)
#pragma unroll
      for (int nt = 0; nt < 4; nt++)
        acc[mt][nt] = __builtin_amdgcn_mfma_f32_16x16x32_f16(af[mt], bf[nt], acc[mt][nt], 0, 0, 0);
    __syncthreads();
  }
#pragma unroll
  for (int nt = 0; nt < 4; nt++){
    int colg = C0 + wc*64 + nt*16 + lr;
    float bv = bias[colg];
#pragma unroll
    for (int mt = 0; mt < 4; mt++)
#pragma unroll
      for (int i = 0; i < 4; i++){
        int row = R0 + wr*64 + mt*16 + quad*4 + i;
        out[(size_t)row*NC + colg] = acc[mt][nt][i] + bv;
      }
  }
}

extern "C" void kernel_launch(void* const* d_in, const int* in_sizes, int n_in,
                              void* d_out, int out_size, void* d_ws, size_t ws_size,
                              hipStream_t stream) {
  const float* x      = (const float*)d_in[0];
  const float* policy = (const float*)d_in[1];
  const float* w_qkv  = (const float*)d_in[2];
  const float* w_proj = (const float*)d_in[3];
  const float* b_proj = (const float*)d_in[4];
  float* out = (float*)d_out;

  f16* x_h     = (f16*)d_ws;
  f16* wqkv_h  = x_h + (size_t)NM*NC;
  f16* wproj_h = wqkv_h + (size_t)QKVC*NC;
  f16* q_h     = wproj_h + (size_t)NC*NC;
  f16* k_h     = q_h + (size_t)NM*NC;
  f16* vt_h    = k_h + (size_t)NM*NC;
  float* vsum_f = (float*)(vt_h + (size_t)NM*NC);
  f16* attn_h  = x_h;   // x dead after gemm_qkv -> reuse

  cvt_f32_f16<<<(NM*NC/4 + 255)/256, 256, 0, stream>>>(x, x_h, NM*NC/4);
  cvt_f32_f16<<<(QKVC*NC/4 + 255)/256, 256, 0, stream>>>(w_qkv, wqkv_h, QKVC*NC/4);
  cvt_f32_f16<<<(NC*NC/4 + 255)/256, 256, 0, stream>>>(w_proj, wproj_h, NC*NC/4);

  gemm_qkv<<<dim3(QKVC/128, NM/128), 256, 0, stream>>>(x_h, wqkv_h, q_h, k_h, vt_h);

  vsum_kernel<<<dim3(NB*NH), 256, 0, stream>>>(vt_h, vsum_f);

  attn_kernel<<<dim3(NB*NH*(NN/128)), 256, 0, stream>>>(q_h, k_h, vt_h, policy, vsum_f, attn_h);

  gemm_proj<<<dim3(NC/128, NM/128), 256, 0, stream>>>(attn_h, wproj_h, b_proj, out);
}

// Round 2
// 463.766 us; speedup vs baseline: 1.3524x; 1.3524x over previous
//
#include <hip/hip_runtime.h>

// Attention with policy-softmax, MI355X (gfx950).
// Shapes: B=16, N=1024, C=768, H=12, hd=64.
// R8: R7 pipeline, register-budget fixed. R7's kA/kB/vt buffers spilled to
// scratch under __launch_bounds__(256,3) (~170 VGPR cap): VGPR_Count=84,
// WRITE_SIZE 24->887MB. R8 keeps the 16-half-step pipeline (K reg-double-
// buffered, VT issued at half-step top, sP per-half 22.5KB LDS) but uses
// __launch_bounds__(256,2) -> 256 VGPR budget, ~210 live, no spill.
// 2 blocks/CU (8 waves) instead of 3; pipeline replaces the lost TLP.
// s_setprio(1) around MFMA clusters (T5). GEMMs unchanged.

#define NB 16
#define NN 1024
#define NC 768
#define NH 12
#define HD 64
#define NM (NB*NN)      // 16384
#define QKVC (3*NC)     // 2304
#define QSCALE 0.18033688011112042f   // 0.125 * log2(e)

typedef _Float16 f16;
typedef _Float16 f16x8 __attribute__((ext_vector_type(8)));
typedef _Float16 f16x4 __attribute__((ext_vector_type(4)));
typedef __fp16 fp16x2 __attribute__((ext_vector_type(2)));   // cvt_pkrtz native type
typedef float f32x4 __attribute__((ext_vector_type(4)));

#if __has_builtin(__builtin_amdgcn_exp2f)
#define EXP2(x) __builtin_amdgcn_exp2f(x)
#else
#define EXP2(x) exp2f(x)
#endif

__device__ inline f16x8 as_f16x8(uint4 u){
  union { uint4 u; f16x8 h; } v; v.u = u; return v.h;
}

// async global->LDS, 16B per lane; lds ptr must be wave-uniform (lane l lands at +l*16B)
__device__ inline void gl_lds16(const f16* g, f16* l){
  __builtin_amdgcn_global_load_lds(
      (const __attribute__((address_space(1))) void*)g,
      (__attribute__((address_space(3))) void*)l, 16, 0, 0);
}

// ---------------- fp32 -> f16 convert ----------------
__global__ void cvt_f32_f16(const float* __restrict__ in, f16* __restrict__ out, int n4){
  int i = blockIdx.x*blockDim.x + threadIdx.x;
  if (i < n4){
    float4 v = ((const float4*)in)[i];
    f16x4 h; h[0]=(f16)v.x; h[1]=(f16)v.y; h[2]=(f16)v.z; h[3]=(f16)v.w;
    ((f16x4*)out)[i] = h;
  }
}

// ---------------- QKV GEMM: [16384,768] x [2304,768]^T, 128x128 tile ----------------
__launch_bounds__(256)
__global__ void gemm_qkv(const f16* __restrict__ X, const f16* __restrict__ W,
                         f16* __restrict__ Q, f16* __restrict__ K, f16* __restrict__ VT){
  __shared__ f16 sA[128*32];   // 8 KB, row-major [row][k], stride 32
  __shared__ f16 sB[128*32];
  const int R0 = blockIdx.y*128, C0 = blockIdx.x*128;
  const int t = threadIdx.x;
  const int w = t >> 6, l = t & 63, quad = l >> 4, lr = l & 15;
  const int wr = w >> 1, wc = w & 1;
  const int row0 = t >> 2, kc0 = (t & 3)*8;
  f32x4 acc[4][4] = {};
  for (int bk = 0; bk < NC; bk += 32){
#pragma unroll
    for (int r = 0; r < 2; r++){
      int row = r*64 + row0;
      gl_lds16(X + (size_t)(R0 + row)*NC + bk + kc0, sA + r*2048 + w*512);
      gl_lds16(W + (size_t)(C0 + row)*NC + bk + kc0, sB + r*2048 + w*512);
    }
    __syncthreads();
    f16x8 af[4], bf[4];
#pragma unroll
    for (int mt = 0; mt < 4; mt++)
      af[mt] = as_f16x8(*(const uint4*)(sA + (wr*64 + mt*16 + lr)*32 + quad*8));
#pragma unroll
    for (int nt = 0; nt < 4; nt++)
      bf[nt] = as_f16x8(*(const uint4*)(sB + (wc*64 + nt*16 + lr)*32 + quad*8));
#pragma unroll
    for (int mt = 0; mt < 4; mt++)
#pragma unroll
      for (int nt = 0; nt < 4; nt++)
        acc[mt][nt] = __builtin_amdgcn_mfma_f32_16x16x32_f16(af[mt], bf[nt], acc[mt][nt], 0, 0, 0);
    __syncthreads();
  }
  // scatter into Q / K / V^T. type uniform per block (128 | 768).
  const int type = C0 / NC;
#pragma unroll
  for (int nt = 0; nt < 4; nt++){
    int colg = C0 + wc*64 + nt*16 + lr;
    int rem  = colg - type*NC;
    int hh = rem >> 6, d = rem & 63;
#pragma unroll
    for (int mt = 0; mt < 4; mt++)
#pragma unroll
      for (int i = 0; i < 4; i++){
        int row = R0 + wr*64 + mt*16 + quad*4 + i;
        int bb = row >> 10, np = row & 1023;
        int bh = bb*NH + hh;
        float a = acc[mt][nt][i];
        if (type == 0)      Q[(bh << 16) + (np << 6) + d] = (f16)(a * QSCALE);
        else if (type == 1) K[(bh << 16) + (np << 6) + d] = (f16)a;
        else                VT[(bh << 16) + (d << 10) + np] = (f16)a;
      }
  }
}

// ---------------- Vsum: column sums of V per (b,h) ----------------
__global__ void vsum_kernel(const f16* __restrict__ VT, float* __restrict__ vsum){
  int bh = blockIdx.x;
  int t = threadIdx.x;
  int row = t >> 2, part = t & 3;
  const uint4* p = (const uint4*)(VT + ((size_t)bh << 16) + row*NN + part*256);
  float s = 0.f;
#pragma unroll
  for (int i = 0; i < 32; i++){
    f16x8 v = as_f16x8(p[i]);
#pragma unroll
    for (int j = 0; j < 8; j++) s += (float)v[j];
  }
  __shared__ float sR[64][4];
  sR[row][part] = s;
  __syncthreads();
  if (t < 64) vsum[bh*64 + t] = sR[t][0] + sR[t][1] + sR[t][2] + sR[t][3];
}

// ---------------- fused policy-softmax attention (no-max-subtract) ----------------
// Grid: 1536 blocks; decode bh = blk % 192 (XCD swizzle: same-bh q-blocks land on
// one XCD), qt = blk / 192. 256 thr = 4 independent waves (32 queries each).
// Q pre-scaled by 0.125*log2e -> e = exp2(acc). Pipeline: 16 half-steps of 64
// keys; K double-buffered in regs (prefetch after S-MFMAs), VT loads issued at
// half-step top. l via ones-MFMA. Epilogue restores exact reference eps
// semantics: out = (O + eps/N*E*Vsum)/(l + eps*E), E = exp2(rowmax).

// --- per-half-step building blocks (expand in attn_kernel scope) ---
#define KLOAD(BUF, CC, HH)                                                    \
  {                                                                           \
    const f16* kp_ = Kln + (size_t)(((CC)*128 + (HH)*64)*HD);                 \
    _Pragma("unroll")                                                         \
    for (int ct = 0; ct < 4; ct++){                                           \
      BUF[2*ct]   = *(const uint4*)(kp_ + ct*16*HD);                          \
      BUF[2*ct+1] = *(const uint4*)(kp_ + ct*16*HD + 32);                     \
    }                                                                         \
  }

#define VTLOAD(CC, HH)                                                        \
  {                                                                           \
    const int off_ = (CC)*128 + (HH)*64;                                      \
    _Pragma("unroll")                                                         \
    for (int nt = 0; nt < 4; nt++){                                           \
      vt[2*nt]   = *(const uint4*)(VTn[nt] + off_);                           \
      vt[2*nt+1] = *(const uint4*)(VTn[nt] + off_ + 32);                      \
    }                                                                         \
  }

#define SQK(KBUF)                                                             \
  __builtin_amdgcn_s_setprio(1);                                              \
  _Pragma("unroll")                                                           \
  for (int ct = 0; ct < 4; ct++){                                             \
    f16x8 k0_ = as_f16x8(KBUF[2*ct]);                                         \
    f16x8 k1_ = as_f16x8(KBUF[2*ct+1]);                                       \
    accA[ct] = __builtin_amdgcn_mfma_f32_16x16x32_f16(k0_, qf[0][0], accA[ct], 0, 0, 0); \
    accA[ct] = __builtin_amdgcn_mfma_f32_16x16x32_f16(k1_, qf[0][1], accA[ct], 0, 0, 0); \
    accB[ct] = __builtin_amdgcn_mfma_f32_16x16x32_f16(k0_, qf[1][0], accB[ct], 0, 0, 0); \
    accB[ct] = __builtin_amdgcn_mfma_f32_16x16x32_f16(k1_, qf[1][1], accB[ct], 0, 0, 0); \
  }                                                                           \
  __builtin_amdgcn_s_setprio(0);

#define SMAX(CC, HH)                                                          \
  {                                                                           \
    const int key0h = (CC)*128 + (HH)*64;                                     \
    float mA = m_run[0], mB = m_run[1];                                       \
    if ((CC) != qt || (HH) != (w >> 1)){                                      \
      _Pragma("unroll")                                                       \
      for (int ct = 0; ct < 4; ct++){                                         \
        const int kb = ct*16 + quad*4;                                        \
        float4 pol4 = *(const float4*)&sPol[key0h + kb];                      \
        const float* p4 = (const float*)&pol4;                                \
        mA = fmaxf(mA, fmaxf(fmaxf(accA[ct][0], accA[ct][1]), fmaxf(accA[ct][2], accA[ct][3]))); \
        mB = fmaxf(mB, fmaxf(fmaxf(accB[ct][0], accB[ct][1]), fmaxf(accB[ct][2], accB[ct][3]))); \
        union { f16x4 v; fp16x2 h[2]; } uA, uB;                               \
        uA.h[0] = __builtin_amdgcn_cvt_pkrtz(EXP2(accA[ct][0])*p4[0], EXP2(accA[ct][1])*p4[1]); \
        uA.h[1] = __builtin_amdgcn_cvt_pkrtz(EXP2(accA[ct][2])*p4[2], EXP2(accA[ct][3])*p4[3]); \
        uB.h[0] = __builtin_amdgcn_cvt_pkrtz(EXP2(accB[ct][0])*p4[0], EXP2(accB[ct][1])*p4[1]); \
        uB.h[1] = __builtin_amdgcn_cvt_pkrtz(EXP2(accB[ct][2])*p4[2], EXP2(accB[ct][3])*p4[3]); \
        *(f16x4*)&sP[w][0][lr][kb] = uA.v;                                    \
        *(f16x4*)&sP[w][1][lr][kb] = uB.v;                                    \
      }                                                                       \
    } else {                                                                  \
      _Pragma("unroll")                                                       \
      for (int ct = 0; ct < 4; ct++){                                         \
        const int kb = ct*16 + quad*4;                                        \
        float4 pol4 = *(const float4*)&sPol[key0h + kb];                      \
        const float* p4 = (const float*)&pol4;                                \
        float eA[4], eB[4];                                                   \
        _Pragma("unroll")                                                     \
        for (int i2 = 0; i2 < 4; i2++){                                       \
          int kg = key0h + kb + i2;                                           \
          float polA = (kg == qrow)      ? 1.0f : p4[i2];                     \
          float polB = (kg == qrow + 16) ? 1.0f : p4[i2];                     \
          mA = fmaxf(mA, accA[ct][i2]); mB = fmaxf(mB, accB[ct][i2]);         \
          eA[i2] = EXP2(accA[ct][i2]) * polA;                                 \
          eB[i2] = EXP2(accB[ct][i2]) * polB;                                 \
        }                                                                     \
        union { f16x4 v; fp16x2 h[2]; } uA, uB;                               \
        uA.h[0] = __builtin_amdgcn_cvt_pkrtz(eA[0], eA[1]);                   \
        uA.h[1] = __builtin_amdgcn_cvt_pkrtz(eA[2], eA[3]);                   \
        uB.h[0] = __builtin_amdgcn_cvt_pkrtz(eB[0], eB[1]);                   \
        uB.h[1] = __builtin_amdgcn_cvt_pkrtz(eB[2], eB[3]);                   \
        *(f16x4*)&sP[w][0][lr][kb] = uA.v;                                    \
        *(f16x4*)&sP[w][1][lr][kb] = uB.v;                                    \
      }                                                                       \
    }                                                                         \
    m_run[0] = mA; m_run[1] = mB;                                             \
  }

#define PVACC                                                                 \
  __builtin_amdgcn_s_setprio(1);                                              \
  _Pragma("unroll")                                                           \
  for (int s8g = 0; s8g < 2; s8g++){                                          \
    f16x8 pfA = as_f16x8(*(const uint4*)&sP[w][0][lr][s8g*32 + quad*8]);      \
    f16x8 pfB = as_f16x8(*(const uint4*)&sP[w][1][lr][s8g*32 + quad*8]);      \
    acc_l[0] = __builtin_amdgcn_mfma_f32_16x16x32_f16(pfA, ones, acc_l[0], 0, 0, 0); \
    acc_l[1] = __builtin_amdgcn_mfma_f32_16x16x32_f16(pfB, ones, acc_l[1], 0, 0, 0); \
    _Pragma("unroll")                                                         \
    for (int nt = 0; nt < 4; nt++){                                           \
      f16x8 vf = as_f16x8(vt[2*nt + s8g]);                                    \
      o[0][nt] = __builtin_amdgcn_mfma_f32_16x16x32_f16(pfA, vf, o[0][nt], 0, 0, 0); \
      o[1][nt] = __builtin_amdgcn_mfma_f32_16x16x32_f16(pfB, vf, o[1][nt], 0, 0, 0); \
    }                                                                         \
  }                                                                           \
  __builtin_amdgcn_s_setprio(0);

__launch_bounds__(256, 2)
__global__ void attn_kernel(const f16* __restrict__ Q, const f16* __restrict__ K,
                            const f16* __restrict__ VT, const float* __restrict__ policy,
                            const float* __restrict__ vsum, f16* __restrict__ O){
  __shared__ f16 sP[4][2][16][72];     // 18432 B (per-half P tile; 72 = 64 + 8 pad, 144B rows)
  __shared__ float sPol[1024];         // 4096 B

  const int blk = blockIdx.x;
  const int bh = blk % (NB*NH);        // stride-192 => same XCD for all qt of a bh
  const int qt = blk / (NB*NH);
  const int b = bh / NH;
  const size_t base = (size_t)bh << 16;

  const int t = threadIdx.x;
  const int w = t >> 6, l = t & 63, quad = l >> 4, lr = l & 15;
  const int q0 = qt*128 + w*32;
  const int qrow = q0 + lr;
  const int h = bh - b*NH;

  *(float4*)&sPol[t*4] = *(const float4*)(policy + b*NN + t*4);

  // Q fragments (pre-scaled), contiguous 16B global reads
  f16x8 qf[2][2];
#pragma unroll
  for (int tq = 0; tq < 2; tq++)
#pragma unroll
    for (int hf = 0; hf < 2; hf++)
      qf[tq][hf] = as_f16x8(*(const uint4*)(Q + base + (size_t)(q0 + tq*16 + lr)*HD + hf*32 + quad*8));

  float vs[4];
#pragma unroll
  for (int nt = 0; nt < 4; nt++) vs[nt] = vsum[bh*64 + nt*16 + lr];

  f16x8 ones;
#pragma unroll
  for (int j = 0; j < 8; j++) ones[j] = (f16)1.0f;

  float m_run[2] = {-INFINITY, -INFINITY};
  f32x4 acc_l[2] = {};
  f32x4 o[2][4] = {};

  // per-lane base pointers (loop bodies use uniform offsets on top of these)
  const f16* Kln = K + base + (size_t)lr*HD + quad*8;
  const f16* VTn[4];
#pragma unroll
  for (int nt = 0; nt < 4; nt++) VTn[nt] = VT + base + (size_t)(nt*16 + lr)*NN + quad*8;

  // stagger chunk start per head-group: same-bh blocks (same XCD) stay in
  // phase for L2 reuse; different bh on an XCD de-correlate.
  const int c0 = (bh >> 3) & 7;
  int c = c0;

  uint4 kA[8], kB[8], vt[8];
  KLOAD(kA, c0, 0);                    // prologue K prefetch (half-step 0)

  __syncthreads();   // sPol ready (also drains prologue loads — once, harmless)

#pragma unroll 1
  for (int i = 0; i < 8; i++){
    const int cn = (c + 1) & 7;
    // ---- half-step 0: consume kA, prefetch kB (this chunk, half 1)
    VTLOAD(c, 0);
    {
      f32x4 accA[4] = {}, accB[4] = {};
      SQK(kA);
      KLOAD(kB, c, 1);
      SMAX(c, 0);
    }
    PVACC;
    // ---- half-step 1: consume kB, prefetch kA (next chunk, half 0)
    VTLOAD(c, 1);
    {
      f32x4 accA[4] = {}, accB[4] = {};
      SQK(kB);
      KLOAD(kA, cn, 0);
      SMAX(c, 1);
    }
    PVACC;
    c = cn;
  }

  // ---- epilogue: out = (O + eps/N * E * Vsum) / (l + eps * E)
#pragma unroll
  for (int tq = 0; tq < 2; tq++){
    float mq = m_run[tq];
    mq = fmaxf(mq, __shfl_xor(mq, 16));
    mq = fmaxf(mq, __shfl_xor(mq, 32));   // per-query (lr) global max, all lanes
#pragma unroll
    for (int i = 0; i < 4; i++){
      float mi = __shfl(mq, quad*4 + i);  // max for query row quad*4+i
      float E  = EXP2(mi);
      float li = acc_l[tq][i];            // row-sum for this query
      float inv = 1.0f / (li + 1e-6f*E);
      float ec  = (1e-6f/1024.0f)*E;
      int row = q0 + tq*16 + quad*4 + i;
      f16* op = O + (size_t)(b*NN + row)*NC + h*HD;
#pragma unroll
      for (int nt = 0; nt < 4; nt++)
        op[nt*16 + lr] = (f16)((o[tq][nt][i] + ec*vs[nt]) * inv);
    }
  }
}

// ---------------- proj GEMM: [16384,768] x [768,768]^T + bias -> fp32, 128x128 ----------------
__launch_bounds__(256)
__global__ void gemm_proj(const f16* __restrict__ A, const f16* __restrict__ W,
                          const float* __restrict__ bias, float* __restrict__ out){
  __shared__ f16 sA[128*32];
  __shared__ f16 sB[128*32];
  const int R0 = blockIdx.y*128, C0 = blockIdx.x*128;
  const int t = threadIdx.x;
  const int w = t >> 6, l = t & 63, quad = l >> 4, lr = l & 15;
  const int wr = w >> 1, wc = w & 1;
  const int row0 = t >> 2, kc0 = (t & 3)*8;
  f32x4 acc[4][4] = {};
  for (int bk = 0; bk < NC; bk += 32){
#pragma unroll
    for (int r = 0; r < 2; r++){
      int row = r*64 + row0;
      gl_lds16(A + (size_t)(R0 + row)*NC + bk + kc0, sA + r*2048 + w*512);
      gl_lds16(W + (size_t)(C0 + row)*NC + bk + kc0, sB + r*2048 + w*512);
    }
    __syncthreads();
    f16x8 af[4], bf[4];
#pragma unroll
    for (int mt = 0; mt < 4; mt++)
      af[mt] = as_f16x8(*(const uint4*)(sA + (wr*64 + mt*16 + lr)*32 + quad*8));
#pragma unroll
    for (int nt = 0; nt < 4; nt++)
      bf[nt] = as_f16x8(*(const uint4*)(sB + (wc*64 + nt*16 + lr)*32 + quad*8));
#pragma unroll
    for (int mt = 0; mt < 4; mt++)
#pragma unroll
      for (int nt = 0; nt < 4; nt++)
        acc[mt][nt] = __builtin_amdgcn_mfma_f32_16x16x32_f16(af[mt], bf[nt], acc[mt][nt], 0, 0, 0);
    __syncthreads();
  }
#pragma unroll
  for (int nt = 0; nt < 4; nt++){
    int colg = C0 + wc*64 + nt*16 + lr;
    float bv = bias[colg];
#pragma unroll
    for (int mt = 0; mt < 4; mt++)
#pragma unroll
      for (int i = 0; i < 4; i++){
        int row = R0 + wr*64 + mt*16 + quad*4 + i;
        out[(size_t)row*NC + colg] = acc[mt][nt][i] + bv;
      }
  }
}

extern "C" void kernel_launch(void* const* d_in, const int* in_sizes, int n_in,
                              void* d_out, int out_size, void* d_ws, size_t ws_size,
                              hipStream_t stream) {
  const float* x      = (const float*)d_in[0];
  const float* policy = (const float*)d_in[1];
  const float* w_qkv  = (const float*)d_in[2];
  const float* w_proj = (const float*)d_in[3];
  const float* b_proj = (const float*)d_in[4];
  float* out = (float*)d_out;

  f16* x_h     = (f16*)d_ws;
  f16* wqkv_h  = x_h + (size_t)NM*NC;
  f16* wproj_h = wqkv_h + (size_t)QKVC*NC;
  f16* q_h     = wproj_h + (size_t)NC*NC;
  f16* k_h     = q_h + (size_t)NM*NC;
  f16* vt_h    = k_h + (size_t)NM*NC;
  float* vsum_f = (float*)(vt_h + (size_t)NM*NC);
  f16* attn_h  = x_h;   // x dead after gemm_qkv -> reuse

  cvt_f32_f16<<<(NM*NC/4 + 255)/256, 256, 0, stream>>>(x, x_h, NM*NC/4);
  cvt_f32_f16<<<(QKVC*NC/4 + 255)/256, 256, 0, stream>>>(w_qkv, wqkv_h, QKVC*NC/4);
  cvt_f32_f16<<<(NC*NC/4 + 255)/256, 256, 0, stream>>>(w_proj, wproj_h, NC*NC/4);

  gemm_qkv<<<dim3(QKVC/128, NM/128), 256, 0, stream>>>(x_h, wqkv_h, q_h, k_h, vt_h);

  vsum_kernel<<<dim3(NB*NH), 256, 0, stream>>>(vt_h, vsum_f);

  attn_kernel<<<dim3(NB*NH*(NN/128)), 256, 0, stream>>>(q_h, k_h, vt_h, policy, vsum_f, attn_h);

  gemm_proj<<<dim3(NC/128, NM/128), 256, 0, stream>>>(attn_h, wproj_h, b_proj, out);
}

// Round 4
// 368.284 us; speedup vs baseline: 1.7030x; 1.2593x over previous
//
#include <hip/hip_runtime.h>

// Attention with policy-softmax, MI355X (gfx950).
// Shapes: B=16, N=1024, C=768, H=12, hd=64.
// R9b: R9 (DMA-pipeline attn: K/VT staged to double-buffered swizzled LDS via
// global_load_lds, counted vmcnt(4), raw s_barrier) + ordering hardening:
// sched_barrier(0) after every asm waitcnt and after every s_barrier, so the
// compiler cannot hoist ds_reads of other waves' staged quarters above the
// barrier (s_barrier is IntrNoMem in LLVM — rule #18 hazard; plausible cause
// of the R9 container hang). Schedule and layout otherwise identical to R9.
// GEMMs unchanged (128x128, global_load_lds width=16).

#define NB 16
#define NN 1024
#define NC 768
#define NH 12
#define HD 64
#define NM (NB*NN)      // 16384
#define QKVC (3*NC)     // 2304
#define QSCALE 0.18033688011112042f   // 0.125 * log2(e)
#define PSTR 68         // sP row stride in f16 (136B)

typedef _Float16 f16;
typedef _Float16 f16x8 __attribute__((ext_vector_type(8)));
typedef _Float16 f16x4 __attribute__((ext_vector_type(4)));
typedef __fp16 fp16x2 __attribute__((ext_vector_type(2)));   // cvt_pkrtz native type
typedef float f32x4 __attribute__((ext_vector_type(4)));

#if __has_builtin(__builtin_amdgcn_exp2f)
#define EXP2(x) __builtin_amdgcn_exp2f(x)
#else
#define EXP2(x) exp2f(x)
#endif

#define MFMA16(a,b,c) __builtin_amdgcn_mfma_f32_16x16x32_f16((a),(b),(c),0,0,0)
#define SCHED_FENCE() __builtin_amdgcn_sched_barrier(0)

__device__ inline f16x8 as_f16x8(uint4 u){
  union { uint4 u; f16x8 h; } v; v.u = u; return v.h;
}

// async global->LDS, 16B per lane; lds ptr must be wave-uniform (lane l lands at +l*16B)
__device__ inline void gl_lds16(const f16* g, f16* l){
  __builtin_amdgcn_global_load_lds(
      (const __attribute__((address_space(1))) void*)g,
      (__attribute__((address_space(3))) void*)l, 16, 0, 0);
}

// ---------------- fp32 -> f16 convert ----------------
__global__ void cvt_f32_f16(const float* __restrict__ in, f16* __restrict__ out, int n4){
  int i = blockIdx.x*blockDim.x + threadIdx.x;
  if (i < n4){
    float4 v = ((const float4*)in)[i];
    f16x4 h; h[0]=(f16)v.x; h[1]=(f16)v.y; h[2]=(f16)v.z; h[3]=(f16)v.w;
    ((f16x4*)out)[i] = h;
  }
}

// ---------------- QKV GEMM: [16384,768] x [2304,768]^T, 128x128 tile ----------------
__launch_bounds__(256)
__global__ void gemm_qkv(const f16* __restrict__ X, const f16* __restrict__ W,
                         f16* __restrict__ Q, f16* __restrict__ K, f16* __restrict__ VT){
  __shared__ f16 sA[128*32];   // 8 KB, row-major [row][k], stride 32
  __shared__ f16 sB[128*32];
  const int R0 = blockIdx.y*128, C0 = blockIdx.x*128;
  const int t = threadIdx.x;
  const int w = t >> 6, l = t & 63, quad = l >> 4, lr = l & 15;
  const int wr = w >> 1, wc = w & 1;
  const int row0 = t >> 2, kc0 = (t & 3)*8;
  f32x4 acc[4][4] = {};
  for (int bk = 0; bk < NC; bk += 32){
#pragma unroll
    for (int r = 0; r < 2; r++){
      int row = r*64 + row0;
      gl_lds16(X + (size_t)(R0 + row)*NC + bk + kc0, sA + r*2048 + w*512);
      gl_lds16(W + (size_t)(C0 + row)*NC + bk + kc0, sB + r*2048 + w*512);
    }
    __syncthreads();
    f16x8 af[4], bf[4];
#pragma unroll
    for (int mt = 0; mt < 4; mt++)
      af[mt] = as_f16x8(*(const uint4*)(sA + (wr*64 + mt*16 + lr)*32 + quad*8));
#pragma unroll
    for (int nt = 0; nt < 4; nt++)
      bf[nt] = as_f16x8(*(const uint4*)(sB + (wc*64 + nt*16 + lr)*32 + quad*8));
#pragma unroll
    for (int mt = 0; mt < 4; mt++)
#pragma unroll
      for (int nt = 0; nt < 4; nt++)
        acc[mt][nt] = MFMA16(af[mt], bf[nt], acc[mt][nt]);
    __syncthreads();
  }
  // scatter into Q / K / V^T. type uniform per block (128 | 768).
  const int type = C0 / NC;
#pragma unroll
  for (int nt = 0; nt < 4; nt++){
    int colg = C0 + wc*64 + nt*16 + lr;
    int rem  = colg - type*NC;
    int hh = rem >> 6, d = rem & 63;
#pragma unroll
    for (int mt = 0; mt < 4; mt++)
#pragma unroll
      for (int i = 0; i < 4; i++){
        int row = R0 + wr*64 + mt*16 + quad*4 + i;
        int bb = row >> 10, np = row & 1023;
        int bh = bb*NH + hh;
        float a = acc[mt][nt][i];
        if (type == 0)      Q[(bh << 16) + (np << 6) + d] = (f16)(a * QSCALE);
        else if (type == 1) K[(bh << 16) + (np << 6) + d] = (f16)a;
        else                VT[(bh << 16) + (d << 10) + np] = (f16)a;
      }
  }
}

// ---------------- Vsum: column sums of V per (b,h) ----------------
__global__ void vsum_kernel(const f16* __restrict__ VT, float* __restrict__ vsum){
  int bh = blockIdx.x;
  int t = threadIdx.x;
  int row = t >> 2, part = t & 3;
  const uint4* p = (const uint4*)(VT + ((size_t)bh << 16) + row*NN + part*256);
  float s = 0.f;
#pragma unroll
  for (int i = 0; i < 32; i++){
    f16x8 v = as_f16x8(p[i]);
#pragma unroll
    for (int j = 0; j < 8; j++) s += (float)v[j];
  }
  __shared__ float sR[64][4];
  sR[row][part] = s;
  __syncthreads();
  if (t < 64) vsum[bh*64 + t] = sR[t][0] + sR[t][1] + sR[t][2] + sR[t][3];
}

// ---------------- fused policy-softmax attention (no-max-subtract) ----------------
// Grid: 1536 blocks; bh = blk % 192 (all 8 q-blocks of a bh march keys in
// lockstep -> L2 temporal sharing), qt = blk / 192. 256 thr = 4 waves, 32
// queries each. Q pre-scaled by 0.125*log2e -> e = exp2(acc).
// 16 steps of 64 keys. Per step: STAGE next K/VT half into LDS (4 gl_lds16,
// XOR-swizzled via pre-swizzled global source), vmcnt(4), barrier, S = K·Q^T
// from LDS (MFMA), softmax*policy -> sP, P·V^T from LDS (MFMA), barrier.
// l via ones-MFMA. Epilogue: out = (O + eps/N*E*Vsum)/(l + eps*E), E=exp2(max).

// stage one 64-key half: K[key0h+row][d] and VT[d][key0h+col] tiles, 8KB each.
// slot s (16B) holds logical (row=s>>3, colslot=(s&7)^(row&7)) -> even bank use.
#define STAGE(BUF, KEY0H)                                                     \
  _Pragma("unroll")                                                           \
  for (int j = 0; j < 2; j++){                                                \
    const int s_  = j*256 + t;                                                \
    const int r_  = s_ >> 3;                                                  \
    const int sl_ = (s_ & 7) ^ (r_ & 7);                                      \
    f16* du_ = (f16*)&sK[BUF][(j*256 + (t & 192))*8];                         \
    f16* dv_ = (f16*)&sVT[BUF][(j*256 + (t & 192))*8];                        \
    gl_lds16(Kg  + (size_t)((KEY0H) + r_)*HD + sl_*8, du_);                   \
    gl_lds16(VTg + (size_t)r_*NN + (KEY0H) + sl_*8,   dv_);                   \
  }

__launch_bounds__(256, 3)
__global__ void attn_kernel(const f16* __restrict__ Q, const f16* __restrict__ K,
                            const f16* __restrict__ VT, const float* __restrict__ policy,
                            const float* __restrict__ vsum, f16* __restrict__ O){
  __shared__ f16 sK[2][4096];          // 16 KB: 64 keys x 64 d, swizzled
  __shared__ f16 sVT[2][4096];         // 16 KB: 64 d x 64 keys, swizzled
  __shared__ f16 sP[4][2][16][PSTR];   // 17408 B
  __shared__ float sPol[1024];         // 4096 B  -> total 53 KB, 3 blocks/CU

  const int blk = blockIdx.x;
  const int bh = blk % (NB*NH);
  const int qt = blk / (NB*NH);
  const int b = bh / NH;
  const size_t base = (size_t)bh << 16;

  const int t = threadIdx.x;
  const int w = t >> 6, l = t & 63, quad = l >> 4, lr = l & 15;
  const int q0 = qt*128 + w*32;
  const int qrow = q0 + lr;
  const int h = bh - b*NH;
  const int xr = lr & 7;                       // row&7 for all tile rows (16-aligned)
  const int kx0 = (quad ^ xr)*8;               // swizzled f16 offset, d 0..31 slot
  const int kx1 = ((4 + quad) ^ xr)*8;         // d 32..63 slot

  *(float4*)&sPol[t*4] = *(const float4*)(policy + b*NN + t*4);

  // Q fragments (pre-scaled), contiguous 16B global reads
  f16x8 qf[2][2];
#pragma unroll
  for (int tq = 0; tq < 2; tq++)
#pragma unroll
    for (int hf = 0; hf < 2; hf++)
      qf[tq][hf] = as_f16x8(*(const uint4*)(Q + base + (size_t)(q0 + tq*16 + lr)*HD + hf*32 + quad*8));

  float vs[4];
#pragma unroll
  for (int nt = 0; nt < 4; nt++) vs[nt] = vsum[bh*64 + nt*16 + lr];

  f16x8 ones;
#pragma unroll
  for (int j = 0; j < 8; j++) ones[j] = (f16)1.0f;

  float m_run[2] = {-INFINITY, -INFINITY};
  f32x4 acc_l[2] = {};
  f32x4 o[2][4] = {};

  const f16* Kg  = K + base;
  const f16* VTg = VT + base;

  // prologue: stage step 0, drain everything (incl. qf/vs vmem + sPol lds)
  STAGE(0, 0);
  asm volatile("s_waitcnt vmcnt(0) lgkmcnt(0)" ::: "memory");
  SCHED_FENCE();
  __builtin_amdgcn_s_barrier();
  SCHED_FENCE();

#pragma unroll 1
  for (int hs = 0; hs < 16; hs++){
    const int cur = hs & 1;
    const int key0h = hs*64;
    if (hs < 15){
      STAGE(cur^1, key0h + 64);
      asm volatile("s_waitcnt vmcnt(4)" ::: "memory");   // drain prev stage, keep 4 in flight
    } else {
      asm volatile("s_waitcnt vmcnt(0)" ::: "memory");
    }
    SCHED_FENCE();
    __builtin_amdgcn_s_barrier();                        // buf[cur] fully staged (all waves)
    SCHED_FENCE();

    const f16* sKc = (const f16*)sK[cur];
    const f16* sVc = (const f16*)sVT[cur];

    // ---- S^T = K · Q^T for 64 keys (rows) x 32 queries
    f32x4 accA[4], accB[4];
#pragma unroll
    for (int ct = 0; ct < 4; ct++){ accA[ct] = (f32x4){0,0,0,0}; accB[ct] = (f32x4){0,0,0,0}; }
    __builtin_amdgcn_s_setprio(1);
#pragma unroll
    for (int ct = 0; ct < 4; ct++){
      const f16* kp = sKc + (ct*16 + lr)*64;
      f16x8 k0 = as_f16x8(*(const uint4*)(kp + kx0));
      f16x8 k1 = as_f16x8(*(const uint4*)(kp + kx1));
      accA[ct] = MFMA16(k0, qf[0][0], accA[ct]);
      accA[ct] = MFMA16(k1, qf[0][1], accA[ct]);
      accB[ct] = MFMA16(k0, qf[1][0], accB[ct]);
      accB[ct] = MFMA16(k1, qf[1][1], accB[ct]);
    }
    __builtin_amdgcn_s_setprio(0);

    // ---- softmax * policy -> sP (per-wave tile), running max
    {
      float mA = m_run[0], mB = m_run[1];
      const bool diag = (hs == 2*qt + (w >> 1));         // wave-uniform
      if (!diag){
#pragma unroll
        for (int ct = 0; ct < 4; ct++){
          const int kb = ct*16 + quad*4;
          float4 pol4 = *(const float4*)&sPol[key0h + kb];
          const float* p4 = (const float*)&pol4;
          mA = fmaxf(mA, fmaxf(fmaxf(accA[ct][0], accA[ct][1]), fmaxf(accA[ct][2], accA[ct][3])));
          mB = fmaxf(mB, fmaxf(fmaxf(accB[ct][0], accB[ct][1]), fmaxf(accB[ct][2], accB[ct][3])));
          union { f16x4 v; fp16x2 h[2]; } uA, uB;
          uA.h[0] = __builtin_amdgcn_cvt_pkrtz(EXP2(accA[ct][0])*p4[0], EXP2(accA[ct][1])*p4[1]);
          uA.h[1] = __builtin_amdgcn_cvt_pkrtz(EXP2(accA[ct][2])*p4[2], EXP2(accA[ct][3])*p4[3]);
          uB.h[0] = __builtin_amdgcn_cvt_pkrtz(EXP2(accB[ct][0])*p4[0], EXP2(accB[ct][1])*p4[1]);
          uB.h[1] = __builtin_amdgcn_cvt_pkrtz(EXP2(accB[ct][2])*p4[2], EXP2(accB[ct][3])*p4[3]);
          *(f16x4*)&sP[w][0][lr][kb] = uA.v;
          *(f16x4*)&sP[w][1][lr][kb] = uB.v;
        }
      } else {
#pragma unroll
        for (int ct = 0; ct < 4; ct++){
          const int kb = ct*16 + quad*4;
          float4 pol4 = *(const float4*)&sPol[key0h + kb];
          const float* p4 = (const float*)&pol4;
          float eA[4], eB[4];
#pragma unroll
          for (int i2 = 0; i2 < 4; i2++){
            int kg = key0h + kb + i2;
            float polA = (kg == qrow)      ? 1.0f : p4[i2];
            float polB = (kg == qrow + 16) ? 1.0f : p4[i2];
            mA = fmaxf(mA, accA[ct][i2]); mB = fmaxf(mB, accB[ct][i2]);
            eA[i2] = EXP2(accA[ct][i2]) * polA;
            eB[i2] = EXP2(accB[ct][i2]) * polB;
          }
          union { f16x4 v; fp16x2 h[2]; } uA, uB;
          uA.h[0] = __builtin_amdgcn_cvt_pkrtz(eA[0], eA[1]);
          uA.h[1] = __builtin_amdgcn_cvt_pkrtz(eA[2], eA[3]);
          uB.h[0] = __builtin_amdgcn_cvt_pkrtz(eB[0], eB[1]);
          uB.h[1] = __builtin_amdgcn_cvt_pkrtz(eB[2], eB[3]);
          *(f16x4*)&sP[w][0][lr][kb] = uA.v;
          *(f16x4*)&sP[w][1][lr][kb] = uB.v;
        }
      }
      m_run[0] = mA; m_run[1] = mB;
    }

    // ---- O += P V^T ; l += P * ones (both MFMA, all operands from LDS)
    __builtin_amdgcn_s_setprio(1);
#pragma unroll
    for (int s8g = 0; s8g < 2; s8g++){
      f16x8 pfA = as_f16x8(*(const uint4*)&sP[w][0][lr][s8g*32 + quad*8]);
      f16x8 pfB = as_f16x8(*(const uint4*)&sP[w][1][lr][s8g*32 + quad*8]);
      acc_l[0] = MFMA16(pfA, ones, acc_l[0]);
      acc_l[1] = MFMA16(pfB, ones, acc_l[1]);
      const int sx = ((s8g*4 + quad) ^ xr)*8;            // swizzled key-slot offset
#pragma unroll
      for (int nt = 0; nt < 4; nt++){
        f16x8 vf = as_f16x8(*(const uint4*)(sVc + (nt*16 + lr)*64 + sx));
        o[0][nt] = MFMA16(pfA, vf, o[0][nt]);
        o[1][nt] = MFMA16(pfB, vf, o[1][nt]);
      }
    }
    __builtin_amdgcn_s_setprio(0);
    SCHED_FENCE();
    __builtin_amdgcn_s_barrier();                        // all waves done with buf[cur]
    SCHED_FENCE();
  }

  // ---- epilogue: out = (O + eps/N * E * Vsum) / (l + eps * E)
#pragma unroll
  for (int tq = 0; tq < 2; tq++){
    float mq = m_run[tq];
    mq = fmaxf(mq, __shfl_xor(mq, 16));
    mq = fmaxf(mq, __shfl_xor(mq, 32));   // per-query (lr) global max, all lanes
#pragma unroll
    for (int i = 0; i < 4; i++){
      float mi = __shfl(mq, quad*4 + i);  // max for query row quad*4+i
      float E  = EXP2(mi);
      float li = acc_l[tq][i];            // row-sum for this query
      float inv = 1.0f / (li + 1e-6f*E);
      float ec  = (1e-6f/1024.0f)*E;
      int row = q0 + tq*16 + quad*4 + i;
      f16* op = O + (size_t)(b*NN + row)*NC + h*HD;
#pragma unroll
      for (int nt = 0; nt < 4; nt++)
        op[nt*16 + lr] = (f16)((o[tq][nt][i] + ec*vs[nt]) * inv);
    }
  }
}

// ---------------- proj GEMM: [16384,768] x [768,768]^T + bias -> fp32, 128x128 ----------------
__launch_bounds__(256)
__global__ void gemm_proj(const f16* __restrict__ A, const f16* __restrict__ W,
                          const float* __restrict__ bias, float* __restrict__ out){
  __shared__ f16 sA[128*32];
  __shared__ f16 sB[128*32];
  const int R0 = blockIdx.y*128, C0 = blockIdx.x*128;
  const int t = threadIdx.x;
  const int w = t >> 6, l = t & 63, quad = l >> 4, lr = l & 15;
  const int wr = w >> 1, wc = w & 1;
  const int row0 = t >> 2, kc0 = (t & 3)*8;
  f32x4 acc[4][4] = {};
  for (int bk = 0; bk < NC; bk += 32){
#pragma unroll
    for (int r = 0; r < 2; r++){
      int row = r*64 + row0;
      gl_lds16(A + (size_t)(R0 + row)*NC + bk + kc0, sA + r*2048 + w*512);
      gl_lds16(W + (size_t)(C0 + row)*NC + bk + kc0, sB + r*2048 + w*512);
    }
    __syncthreads();
    f16x8 af[4], bf[4];
#pragma unroll
    for (int mt = 0; mt < 4; mt++)
      af[mt] = as_f16x8(*(const uint4*)(sA + (wr*64 + mt*16 + lr)*32 + quad*8));
#pragma unroll
    for (int nt = 0; nt < 4; nt++)
      bf[nt] = as_f16x8(*(const uint4*)(sB + (wc*64 + nt*16 + lr)*32 + quad*8));
#pragma unroll
    for (int mt = 0; mt < 4; mt++)
#pragma unroll
      for (int nt = 0; nt < 4; nt++)
        acc[mt][nt] = MFMA16(af[mt], bf[nt], acc[mt][nt]);
    __syncthreads();
  }
#pragma unroll
  for (int nt = 0; nt < 4; nt++){
    int colg = C0 + wc*64 + nt*16 + lr;
    float bv = bias[colg];
#pragma unroll
    for (int mt = 0; mt < 4; mt++)
#pragma unroll
      for (int i = 0; i < 4; i++){
        int row = R0 + wr*64 + mt*16 + quad*4 + i;
        out[(size_t)row*NC + colg] = acc[mt][nt][i] + bv;
      }
  }
}

extern "C" void kernel_launch(void* const* d_in, const int* in_sizes, int n_in,
                              void* d_out, int out_size, void* d_ws, size_t ws_size,
                              hipStream_t stream) {
  const float* x      = (const float*)d_in[0];
  const float* policy = (const float*)d_in[1];
  const float* w_qkv  = (const float*)d_in[2];
  const float* w_proj = (const float*)d_in[3];
  const float* b_proj = (const float*)d_in[4];
  float* out = (float*)d_out;

  f16* x_h     = (f16*)d_ws;
  f16* wqkv_h  = x_h + (size_t)NM*NC;
  f16* wproj_h = wqkv_h + (size_t)QKVC*NC;
  f16* q_h     = wproj_h + (size_t)NC*NC;
  f16* k_h     = q_h + (size_t)NM*NC;
  f16* vt_h    = k_h + (size_t)NM*NC;
  float* vsum_f = (float*)(vt_h + (size_t)NM*NC);
  f16* attn_h  = x_h;   // x dead after gemm_qkv -> reuse

  cvt_f32_f16<<<(NM*NC/4 + 255)/256, 256, 0, stream>>>(x, x_h, NM*NC/4);
  cvt_f32_f16<<<(QKVC*NC/4 + 255)/256, 256, 0, stream>>>(w_qkv, wqkv_h, QKVC*NC/4);
  cvt_f32_f16<<<(NC*NC/4 + 255)/256, 256, 0, stream>>>(w_proj, wproj_h, NC*NC/4);

  gemm_qkv<<<dim3(QKVC/128, NM/128), 256, 0, stream>>>(x_h, wqkv_h, q_h, k_h, vt_h);

  vsum_kernel<<<dim3(NB*NH), 256, 0, stream>>>(vt_h, vsum_f);

  attn_kernel<<<dim3(NB*NH*(NN/128)), 256, 0, stream>>>(q_h, k_h, vt_h, policy, vsum_f, attn_h);

  gemm_proj<<<dim3(NC/128, NM/128), 256, 0, stream>>>(attn_h, wproj_h, b_proj, out);
}

// Round 5
// 344.554 us; speedup vs baseline: 1.8203x; 1.0689x over previous
//
#include <hip/hip_runtime.h>

// Attention with policy-softmax, MI355X (gfx950).
// Shapes: B=16, N=1024, C=768, H=12, hd=64.
// R10: GEMMs get the R9b-proven DMA pipeline — double-buffered LDS tiles,
// STAGE(t+1) before compute(t), counted s_waitcnt vmcnt(4) (never 0 in-loop),
// raw s_barrier + sched_barrier(0) fences, setprio around MFMA. Replaces the
// __syncthreads() full-drain per K-step (the m97-structure stall). LDS 32KB,
// 5 blocks/CU. cvt launches merged into one. attn unchanged from R9b
// (465->368us; attn ~106us).

#define NB 16
#define NN 1024
#define NC 768
#define NH 12
#define HD 64
#define NM (NB*NN)      // 16384
#define QKVC (3*NC)     // 2304
#define QSCALE 0.18033688011112042f   // 0.125 * log2(e)
#define PSTR 68         // sP row stride in f16 (136B)

typedef _Float16 f16;
typedef _Float16 f16x8 __attribute__((ext_vector_type(8)));
typedef _Float16 f16x4 __attribute__((ext_vector_type(4)));
typedef __fp16 fp16x2 __attribute__((ext_vector_type(2)));   // cvt_pkrtz native type
typedef float f32x4 __attribute__((ext_vector_type(4)));

#if __has_builtin(__builtin_amdgcn_exp2f)
#define EXP2(x) __builtin_amdgcn_exp2f(x)
#else
#define EXP2(x) exp2f(x)
#endif

#define MFMA16(a,b,c) __builtin_amdgcn_mfma_f32_16x16x32_f16((a),(b),(c),0,0,0)
#define SCHED_FENCE() __builtin_amdgcn_sched_barrier(0)

__device__ inline f16x8 as_f16x8(uint4 u){
  union { uint4 u; f16x8 h; } v; v.u = u; return v.h;
}

// async global->LDS, 16B per lane; lds ptr must be wave-uniform (lane l lands at +l*16B)
__device__ inline void gl_lds16(const f16* g, f16* l){
  __builtin_amdgcn_global_load_lds(
      (const __attribute__((address_space(1))) void*)g,
      (__attribute__((address_space(3))) void*)l, 16, 0, 0);
}

// ---------------- fp32 -> f16 convert (all three tensors, one launch) ----------------
#define CVT_N1 (NM*NC/4)      // 3145728
#define CVT_N2 (QKVC*NC/4)    // 442368
#define CVT_N3 (NC*NC/4)      // 147456
__global__ void cvt_all(const float* __restrict__ x, const float* __restrict__ wq,
                        const float* __restrict__ wp, f16* __restrict__ xh,
                        f16* __restrict__ wqh, f16* __restrict__ wph){
  int i = blockIdx.x*blockDim.x + threadIdx.x;
  const float* in; f16* out; int j;
  if (i < CVT_N1){ in = x; out = xh; j = i; }
  else if (i < CVT_N1 + CVT_N2){ in = wq; out = wqh; j = i - CVT_N1; }
  else { in = wp; out = wph; j = i - CVT_N1 - CVT_N2; }
  float4 v = ((const float4*)in)[j];
  f16x4 h; h[0]=(f16)v.x; h[1]=(f16)v.y; h[2]=(f16)v.z; h[3]=(f16)v.w;
  ((f16x4*)out)[j] = h;
}

// ---------------- pipelined 128x128 GEMM body (shared by qkv/proj) ----------------
// double-buffered sA/sB [2][128][32]; STAGE(next) -> vmcnt(4) -> barrier ->
// ds_read+MFMA -> barrier. 24 K-steps (K=768, BK=32).
#define GEMM_STAGE(SRC_A, SRC_B, BUF, BK)                                     \
  _Pragma("unroll")                                                           \
  for (int r = 0; r < 2; r++){                                                \
    int row = r*64 + row0;                                                    \
    gl_lds16(SRC_A + (size_t)(R0 + row)*NC + (BK) + kc0, sA[BUF] + r*2048 + w*512); \
    gl_lds16(SRC_B + (size_t)(C0 + row)*NC + (BK) + kc0, sB[BUF] + r*2048 + w*512); \
  }

#define GEMM_PIPELINE(SRC_A, SRC_B)                                           \
  GEMM_STAGE(SRC_A, SRC_B, 0, 0);                                             \
  asm volatile("s_waitcnt vmcnt(0)" ::: "memory");                            \
  SCHED_FENCE();                                                              \
  __builtin_amdgcn_s_barrier();                                               \
  SCHED_FENCE();                                                              \
  _Pragma("unroll 1")                                                         \
  for (int kt = 0; kt < 24; kt++){                                            \
    const int cur = kt & 1;                                                   \
    if (kt < 23){                                                             \
      GEMM_STAGE(SRC_A, SRC_B, cur^1, (kt+1)*32);                             \
      asm volatile("s_waitcnt vmcnt(4)" ::: "memory");                        \
    } else {                                                                  \
      asm volatile("s_waitcnt vmcnt(0)" ::: "memory");                        \
    }                                                                         \
    SCHED_FENCE();                                                            \
    __builtin_amdgcn_s_barrier();                                             \
    SCHED_FENCE();                                                            \
    f16x8 af[4], bf[4];                                                       \
    _Pragma("unroll")                                                         \
    for (int mt = 0; mt < 4; mt++)                                            \
      af[mt] = as_f16x8(*(const uint4*)(sA[cur] + (wr*64 + mt*16 + lr)*32 + quad*8)); \
    _Pragma("unroll")                                                         \
    for (int nt = 0; nt < 4; nt++)                                            \
      bf[nt] = as_f16x8(*(const uint4*)(sB[cur] + (wc*64 + nt*16 + lr)*32 + quad*8)); \
    __builtin_amdgcn_s_setprio(1);                                            \
    _Pragma("unroll")                                                         \
    for (int mt = 0; mt < 4; mt++)                                            \
      _Pragma("unroll")                                                       \
      for (int nt = 0; nt < 4; nt++)                                          \
        acc[mt][nt] = MFMA16(af[mt], bf[nt], acc[mt][nt]);                    \
    __builtin_amdgcn_s_setprio(0);                                            \
    SCHED_FENCE();                                                            \
    __builtin_amdgcn_s_barrier();                                             \
    SCHED_FENCE();                                                            \
  }

// ---------------- QKV GEMM: [16384,768] x [2304,768]^T, 128x128 tile ----------------
__launch_bounds__(256)
__global__ void gemm_qkv(const f16* __restrict__ X, const f16* __restrict__ W,
                         f16* __restrict__ Q, f16* __restrict__ K, f16* __restrict__ VT){
  __shared__ f16 sA[2][128*32];   // 2 x 8 KB
  __shared__ f16 sB[2][128*32];
  const int R0 = blockIdx.y*128, C0 = blockIdx.x*128;
  const int t = threadIdx.x;
  const int w = t >> 6, l = t & 63, quad = l >> 4, lr = l & 15;
  const int wr = w >> 1, wc = w & 1;
  const int row0 = t >> 2, kc0 = (t & 3)*8;
  f32x4 acc[4][4] = {};
  GEMM_PIPELINE(X, W);
  // scatter into Q / K / V^T. type uniform per block (128 | 768).
  const int type = C0 / NC;
#pragma unroll
  for (int nt = 0; nt < 4; nt++){
    int colg = C0 + wc*64 + nt*16 + lr;
    int rem  = colg - type*NC;
    int hh = rem >> 6, d = rem & 63;
#pragma unroll
    for (int mt = 0; mt < 4; mt++)
#pragma unroll
      for (int i = 0; i < 4; i++){
        int row = R0 + wr*64 + mt*16 + quad*4 + i;
        int bb = row >> 10, np = row & 1023;
        int bh = bb*NH + hh;
        float a = acc[mt][nt][i];
        if (type == 0)      Q[(bh << 16) + (np << 6) + d] = (f16)(a * QSCALE);
        else if (type == 1) K[(bh << 16) + (np << 6) + d] = (f16)a;
        else                VT[(bh << 16) + (d << 10) + np] = (f16)a;
      }
  }
}

// ---------------- Vsum: column sums of V per (b,h) ----------------
__global__ void vsum_kernel(const f16* __restrict__ VT, float* __restrict__ vsum){
  int bh = blockIdx.x;
  int t = threadIdx.x;
  int row = t >> 2, part = t & 3;
  const uint4* p = (const uint4*)(VT + ((size_t)bh << 16) + row*NN + part*256);
  float s = 0.f;
#pragma unroll
  for (int i = 0; i < 32; i++){
    f16x8 v = as_f16x8(p[i]);
#pragma unroll
    for (int j = 0; j < 8; j++) s += (float)v[j];
  }
  __shared__ float sR[64][4];
  sR[row][part] = s;
  __syncthreads();
  if (t < 64) vsum[bh*64 + t] = sR[t][0] + sR[t][1] + sR[t][2] + sR[t][3];
}

// ---------------- fused policy-softmax attention (no-max-subtract) ----------------
// (unchanged from R9b — DMA pipeline, verified 465->368us)
#define STAGE(BUF, KEY0H)                                                     \
  _Pragma("unroll")                                                           \
  for (int j = 0; j < 2; j++){                                                \
    const int s_  = j*256 + t;                                                \
    const int r_  = s_ >> 3;                                                  \
    const int sl_ = (s_ & 7) ^ (r_ & 7);                                      \
    f16* du_ = (f16*)&sK[BUF][(j*256 + (t & 192))*8];                         \
    f16* dv_ = (f16*)&sVT[BUF][(j*256 + (t & 192))*8];                        \
    gl_lds16(Kg  + (size_t)((KEY0H) + r_)*HD + sl_*8, du_);                   \
    gl_lds16(VTg + (size_t)r_*NN + (KEY0H) + sl_*8,   dv_);                   \
  }

__launch_bounds__(256, 3)
__global__ void attn_kernel(const f16* __restrict__ Q, const f16* __restrict__ K,
                            const f16* __restrict__ VT, const float* __restrict__ policy,
                            const float* __restrict__ vsum, f16* __restrict__ O){
  __shared__ f16 sK[2][4096];          // 16 KB: 64 keys x 64 d, swizzled
  __shared__ f16 sVT[2][4096];         // 16 KB: 64 d x 64 keys, swizzled
  __shared__ f16 sP[4][2][16][PSTR];   // 17408 B
  __shared__ float sPol[1024];         // 4096 B  -> total 53 KB, 3 blocks/CU

  const int blk = blockIdx.x;
  const int bh = blk % (NB*NH);
  const int qt = blk / (NB*NH);
  const int b = bh / NH;
  const size_t base = (size_t)bh << 16;

  const int t = threadIdx.x;
  const int w = t >> 6, l = t & 63, quad = l >> 4, lr = l & 15;
  const int q0 = qt*128 + w*32;
  const int qrow = q0 + lr;
  const int h = bh - b*NH;
  const int xr = lr & 7;                       // row&7 for all tile rows (16-aligned)
  const int kx0 = (quad ^ xr)*8;               // swizzled f16 offset, d 0..31 slot
  const int kx1 = ((4 + quad) ^ xr)*8;         // d 32..63 slot

  *(float4*)&sPol[t*4] = *(const float4*)(policy + b*NN + t*4);

  // Q fragments (pre-scaled), contiguous 16B global reads
  f16x8 qf[2][2];
#pragma unroll
  for (int tq = 0; tq < 2; tq++)
#pragma unroll
    for (int hf = 0; hf < 2; hf++)
      qf[tq][hf] = as_f16x8(*(const uint4*)(Q + base + (size_t)(q0 + tq*16 + lr)*HD + hf*32 + quad*8));

  float vs[4];
#pragma unroll
  for (int nt = 0; nt < 4; nt++) vs[nt] = vsum[bh*64 + nt*16 + lr];

  f16x8 ones;
#pragma unroll
  for (int j = 0; j < 8; j++) ones[j] = (f16)1.0f;

  float m_run[2] = {-INFINITY, -INFINITY};
  f32x4 acc_l[2] = {};
  f32x4 o[2][4] = {};

  const f16* Kg  = K + base;
  const f16* VTg = VT + base;

  // prologue: stage step 0, drain everything (incl. qf/vs vmem + sPol lds)
  STAGE(0, 0);
  asm volatile("s_waitcnt vmcnt(0) lgkmcnt(0)" ::: "memory");
  SCHED_FENCE();
  __builtin_amdgcn_s_barrier();
  SCHED_FENCE();

#pragma unroll 1
  for (int hs = 0; hs < 16; hs++){
    const int cur = hs & 1;
    const int key0h = hs*64;
    if (hs < 15){
      STAGE(cur^1, key0h + 64);
      asm volatile("s_waitcnt vmcnt(4)" ::: "memory");   // drain prev stage, keep 4 in flight
    } else {
      asm volatile("s_waitcnt vmcnt(0)" ::: "memory");
    }
    SCHED_FENCE();
    __builtin_amdgcn_s_barrier();                        // buf[cur] fully staged (all waves)
    SCHED_FENCE();

    const f16* sKc = (const f16*)sK[cur];
    const f16* sVc = (const f16*)sVT[cur];

    // ---- S^T = K · Q^T for 64 keys (rows) x 32 queries
    f32x4 accA[4], accB[4];
#pragma unroll
    for (int ct = 0; ct < 4; ct++){ accA[ct] = (f32x4){0,0,0,0}; accB[ct] = (f32x4){0,0,0,0}; }
    __builtin_amdgcn_s_setprio(1);
#pragma unroll
    for (int ct = 0; ct < 4; ct++){
      const f16* kp = sKc + (ct*16 + lr)*64;
      f16x8 k0 = as_f16x8(*(const uint4*)(kp + kx0));
      f16x8 k1 = as_f16x8(*(const uint4*)(kp + kx1));
      accA[ct] = MFMA16(k0, qf[0][0], accA[ct]);
      accA[ct] = MFMA16(k1, qf[0][1], accA[ct]);
      accB[ct] = MFMA16(k0, qf[1][0], accB[ct]);
      accB[ct] = MFMA16(k1, qf[1][1], accB[ct]);
    }
    __builtin_amdgcn_s_setprio(0);

    // ---- softmax * policy -> sP (per-wave tile), running max
    {
      float mA = m_run[0], mB = m_run[1];
      const bool diag = (hs == 2*qt + (w >> 1));         // wave-uniform
      if (!diag){
#pragma unroll
        for (int ct = 0; ct < 4; ct++){
          const int kb = ct*16 + quad*4;
          float4 pol4 = *(const float4*)&sPol[key0h + kb];
          const float* p4 = (const float*)&pol4;
          mA = fmaxf(mA, fmaxf(fmaxf(accA[ct][0], accA[ct][1]), fmaxf(accA[ct][2], accA[ct][3])));
          mB = fmaxf(mB, fmaxf(fmaxf(accB[ct][0], accB[ct][1]), fmaxf(accB[ct][2], accB[ct][3])));
          union { f16x4 v; fp16x2 h[2]; } uA, uB;
          uA.h[0] = __builtin_amdgcn_cvt_pkrtz(EXP2(accA[ct][0])*p4[0], EXP2(accA[ct][1])*p4[1]);
          uA.h[1] = __builtin_amdgcn_cvt_pkrtz(EXP2(accA[ct][2])*p4[2], EXP2(accA[ct][3])*p4[3]);
          uB.h[0] = __builtin_amdgcn_cvt_pkrtz(EXP2(accB[ct][0])*p4[0], EXP2(accB[ct][1])*p4[1]);
          uB.h[1] = __builtin_amdgcn_cvt_pkrtz(EXP2(accB[ct][2])*p4[2], EXP2(accB[ct][3])*p4[3]);
          *(f16x4*)&sP[w][0][lr][kb] = uA.v;
          *(f16x4*)&sP[w][1][lr][kb] = uB.v;
        }
      } else {
#pragma unroll
        for (int ct = 0; ct < 4; ct++){
          const int kb = ct*16 + quad*4;
          float4 pol4 = *(const float4*)&sPol[key0h + kb];
          const float* p4 = (const float*)&pol4;
          float eA[4], eB[4];
#pragma unroll
          for (int i2 = 0; i2 < 4; i2++){
            int kg = key0h + kb + i2;
            float polA = (kg == qrow)      ? 1.0f : p4[i2];
            float polB = (kg == qrow + 16) ? 1.0f : p4[i2];
            mA = fmaxf(mA, accA[ct][i2]); mB = fmaxf(mB, accB[ct][i2]);
            eA[i2] = EXP2(accA[ct][i2]) * polA;
            eB[i2] = EXP2(accB[ct][i2]) * polB;
          }
          union { f16x4 v; fp16x2 h[2]; } uA, uB;
          uA.h[0] = __builtin_amdgcn_cvt_pkrtz(eA[0], eA[1]);
          uA.h[1] = __builtin_amdgcn_cvt_pkrtz(eA[2], eA[3]);
          uB.h[0] = __builtin_amdgcn_cvt_pkrtz(eB[0], eB[1]);
          uB.h[1] = __builtin_amdgcn_cvt_pkrtz(eB[2], eB[3]);
          *(f16x4*)&sP[w][0][lr][kb] = uA.v;
          *(f16x4*)&sP[w][1][lr][kb] = uB.v;
        }
      }
      m_run[0] = mA; m_run[1] = mB;
    }

    // ---- O += P V^T ; l += P * ones (both MFMA, all operands from LDS)
    __builtin_amdgcn_s_setprio(1);
#pragma unroll
    for (int s8g = 0; s8g < 2; s8g++){
      f16x8 pfA = as_f16x8(*(const uint4*)&sP[w][0][lr][s8g*32 + quad*8]);
      f16x8 pfB = as_f16x8(*(const uint4*)&sP[w][1][lr][s8g*32 + quad*8]);
      acc_l[0] = MFMA16(pfA, ones, acc_l[0]);
      acc_l[1] = MFMA16(pfB, ones, acc_l[1]);
      const int sx = ((s8g*4 + quad) ^ xr)*8;            // swizzled key-slot offset
#pragma unroll
      for (int nt = 0; nt < 4; nt++){
        f16x8 vf = as_f16x8(*(const uint4*)(sVc + (nt*16 + lr)*64 + sx));
        o[0][nt] = MFMA16(pfA, vf, o[0][nt]);
        o[1][nt] = MFMA16(pfB, vf, o[1][nt]);
      }
    }
    __builtin_amdgcn_s_setprio(0);
    SCHED_FENCE();
    __builtin_amdgcn_s_barrier();                        // all waves done with buf[cur]
    SCHED_FENCE();
  }

  // ---- epilogue: out = (O + eps/N * E * Vsum) / (l + eps * E)
#pragma unroll
  for (int tq = 0; tq < 2; tq++){
    float mq = m_run[tq];
    mq = fmaxf(mq, __shfl_xor(mq, 16));
    mq = fmaxf(mq, __shfl_xor(mq, 32));   // per-query (lr) global max, all lanes
#pragma unroll
    for (int i = 0; i < 4; i++){
      float mi = __shfl(mq, quad*4 + i);  // max for query row quad*4+i
      float E  = EXP2(mi);
      float li = acc_l[tq][i];            // row-sum for this query
      float inv = 1.0f / (li + 1e-6f*E);
      float ec  = (1e-6f/1024.0f)*E;
      int row = q0 + tq*16 + quad*4 + i;
      f16* op = O + (size_t)(b*NN + row)*NC + h*HD;
#pragma unroll
      for (int nt = 0; nt < 4; nt++)
        op[nt*16 + lr] = (f16)((o[tq][nt][i] + ec*vs[nt]) * inv);
    }
  }
}

// ---------------- proj GEMM: [16384,768] x [768,768]^T + bias -> fp32, 128x128 ----------------
__launch_bounds__(256)
__global__ void gemm_proj(const f16* __restrict__ A, const f16* __restrict__ W,
                          const float* __restrict__ bias, float* __restrict__ out){
  __shared__ f16 sA[2][128*32];
  __shared__ f16 sB[2][128*32];
  const int R0 = blockIdx.y*128, C0 = blockIdx.x*128;
  const int t = threadIdx.x;
  const int w = t >> 6, l = t & 63, quad = l >> 4, lr = l & 15;
  const int wr = w >> 1, wc = w & 1;
  const int row0 = t >> 2, kc0 = (t & 3)*8;
  f32x4 acc[4][4] = {};
  GEMM_PIPELINE(A, W);
#pragma unroll
  for (int nt = 0; nt < 4; nt++){
    int colg = C0 + wc*64 + nt*16 + lr;
    float bv = bias[colg];
#pragma unroll
    for (int mt = 0; mt < 4; mt++)
#pragma unroll
      for (int i = 0; i < 4; i++){
        int row = R0 + wr*64 + mt*16 + quad*4 + i;
        out[(size_t)row*NC + colg] = acc[mt][nt][i] + bv;
      }
  }
}

extern "C" void kernel_launch(void* const* d_in, const int* in_sizes, int n_in,
                              void* d_out, int out_size, void* d_ws, size_t ws_size,
                              hipStream_t stream) {
  const float* x      = (const float*)d_in[0];
  const float* policy = (const float*)d_in[1];
  const float* w_qkv  = (const float*)d_in[2];
  const float* w_proj = (const float*)d_in[3];
  const float* b_proj = (const float*)d_in[4];
  float* out = (float*)d_out;

  f16* x_h     = (f16*)d_ws;
  f16* wqkv_h  = x_h + (size_t)NM*NC;
  f16* wproj_h = wqkv_h + (size_t)QKVC*NC;
  f16* q_h     = wproj_h + (size_t)NC*NC;
  f16* k_h     = q_h + (size_t)NM*NC;
  f16* vt_h    = k_h + (size_t)NM*NC;
  float* vsum_f = (float*)(vt_h + (size_t)NM*NC);
  f16* attn_h  = x_h;   // x dead after gemm_qkv -> reuse

  cvt_all<<<(CVT_N1+CVT_N2+CVT_N3)/256, 256, 0, stream>>>(x, w_qkv, w_proj, x_h, wqkv_h, wproj_h);

  gemm_qkv<<<dim3(QKVC/128, NM/128), 256, 0, stream>>>(x_h, wqkv_h, q_h, k_h, vt_h);

  vsum_kernel<<<dim3(NB*NH), 256, 0, stream>>>(vt_h, vsum_f);

  attn_kernel<<<dim3(NB*NH*(NN/128)), 256, 0, stream>>>(q_h, k_h, vt_h, policy, vsum_f, attn_h);

  gemm_proj<<<dim3(NC/128, NM/128), 256, 0, stream>>>(attn_h, wproj_h, b_proj, out);
}